// Round 1
// baseline (1296.842 us; speedup 1.0000x reference)
//
#include <hip/hip_runtime.h>
#include <hip/hip_bf16.h>
#include <cstdint>

// ---------------- problem constants ----------------
namespace {
constexpr int BB = 4;
constexpr int CC = 27;
constexpr int HW = 448 * 448;                 // 200704
constexpr long long CHW = (long long)CC * HW; // 5419008
constexpr int NP = 196;                        // patch positions
constexpr int NSTRIP = HW / NP;                // 1024
constexpr int GG = 56 * 56;                    // 3136 pooled positions
constexpr int DSPLIT = 16;
constexpr int DTOT = CC * NSTRIP;              // 27648
constexpr int DCHUNK = DTOT / DSPLIT;          // 1728
constexpr float SCALE_P = 0.0060140449f;       // 1/sqrt(27648)
constexpr float SCALE_G = 0.1924500897f;       // 1/sqrt(27)
constexpr float EPSV = 1e-5f;
}

__device__ __forceinline__ float bf2f(unsigned short u) {
    return __uint_as_float(((uint32_t)u) << 16);
}

// ---------------- 1. GroupNorm stats ----------------
__global__ void k_gn_partial(const float* __restrict__ x, float* __restrict__ part) {
    int blk = blockIdx.x;          // BB*1024 blocks
    int b = blk >> 10;
    int chunk = blk & 1023;
    const int CLEN = (int)(CHW / 1024);   // 5292
    const float* p = x + (size_t)b * CHW + (size_t)chunk * CLEN;
    float s = 0.f, ss = 0.f;
    for (int i = threadIdx.x; i < CLEN; i += 256) {
        float v = p[i];
        s += v; ss += v * v;
    }
    for (int o = 32; o; o >>= 1) { s += __shfl_down(s, o); ss += __shfl_down(ss, o); }
    __shared__ float ls[4], lss[4];
    int wid = threadIdx.x >> 6, lane = threadIdx.x & 63;
    if (lane == 0) { ls[wid] = s; lss[wid] = ss; }
    __syncthreads();
    if (threadIdx.x == 0) {
        float S = ls[0] + ls[1] + ls[2] + ls[3];
        float SS = lss[0] + lss[1] + lss[2] + lss[3];
        part[blk * 2] = S; part[blk * 2 + 1] = SS;
    }
}

__global__ void k_gn_final(const float* __restrict__ part, float* __restrict__ stats) {
    int b = blockIdx.x;
    float s = 0.f, ss = 0.f;
    for (int i = threadIdx.x; i < 1024; i += 256) {
        s += part[(b * 1024 + i) * 2];
        ss += part[(b * 1024 + i) * 2 + 1];
    }
    for (int o = 32; o; o >>= 1) { s += __shfl_down(s, o); ss += __shfl_down(ss, o); }
    __shared__ float ls[4], lss[4];
    int wid = threadIdx.x >> 6, lane = threadIdx.x & 63;
    if (lane == 0) { ls[wid] = s; lss[wid] = ss; }
    __syncthreads();
    if (threadIdx.x == 0) {
        float S = ls[0] + ls[1] + ls[2] + ls[3];
        float SS = lss[0] + lss[1] + lss[2] + lss[3];
        float mean = S / (float)CHW;
        float var = SS / (float)CHW - mean * mean;
        stats[b * 2] = mean;
        stats[b * 2 + 1] = rsqrtf(var + EPSV);
    }
}

// ---------------- 2. GN-apply + QKV conv1x1 (-> bf16) ----------------
__global__ void k_qkv(const float* __restrict__ x, const float* __restrict__ stats,
                      const float* __restrict__ qw, const float* __restrict__ qb,
                      const float* __restrict__ kw, const float* __restrict__ kb,
                      const float* __restrict__ vw, const float* __restrict__ vb,
                      const float* __restrict__ gnw, const float* __restrict__ gnb,
                      __hip_bfloat16* __restrict__ q, __hip_bfloat16* __restrict__ k,
                      __hip_bfloat16* __restrict__ v) {
    __shared__ float W[2322];
    for (int i = threadIdx.x; i < 729; i += 256) {
        W[i] = qw[i]; W[729 + i] = kw[i]; W[1458 + i] = vw[i];
    }
    if (threadIdx.x < 27) {
        int i = threadIdx.x;
        W[2187 + i] = qb[i]; W[2214 + i] = kb[i]; W[2241 + i] = vb[i];
        W[2268 + i] = gnw[i]; W[2295 + i] = gnb[i];
    }
    __syncthreads();
    int p = blockIdx.x * 256 + threadIdx.x;   // 0..802815
    int b = p / HW;
    int hw = p - b * HW;
    float mean = stats[b * 2], rstd = stats[b * 2 + 1];
    float xn[27];
    const float* xp = x + (size_t)b * CHW + hw;
#pragma unroll
    for (int c = 0; c < 27; c++)
        xn[c] = (xp[(size_t)c * HW] - mean) * rstd * W[2268 + c] + W[2295 + c];
    size_t ob = (size_t)b * CHW + hw;
#pragma unroll 1
    for (int o = 0; o < 27; o++) {
        float aq = W[2187 + o], ak = W[2214 + o], av = W[2241 + o];
#pragma unroll
        for (int c = 0; c < 27; c++) {
            float xv = xn[c];
            aq += W[o * 27 + c] * xv;
            ak += W[729 + o * 27 + c] * xv;
            av += W[1458 + o * 27 + c] * xv;
        }
        q[ob + (size_t)o * HW] = __float2bfloat16(aq);
        k[ob + (size_t)o * HW] = __float2bfloat16(ak);
        v[ob + (size_t)o * HW] = __float2bfloat16(av);
    }
}

// ---------------- 3. 8x8 avg pool -> transposed [b][g][27] ----------------
__global__ void k_pool(const __hip_bfloat16* __restrict__ src, float* __restrict__ dst) {
    int idx = blockIdx.x * 256 + threadIdx.x;  // < 4*27*3136 = 338688
    int g = idx % GG;
    int t = idx / GG;
    int c = t % 27;
    int b = t / 27;
    int gh = g / 56, gw = g - (g / 56) * 56;
    const ushort* sp = (const ushort*)src + (size_t)(b * 27 + c) * HW + (size_t)(gh * 8) * 448 + gw * 8;
    float s = 0.f;
#pragma unroll
    for (int r = 0; r < 8; r++) {
        const ushort4 a = *reinterpret_cast<const ushort4*>(sp + r * 448);
        const ushort4 d = *reinterpret_cast<const ushort4*>(sp + r * 448 + 4);
        s += bf2f(a.x) + bf2f(a.y) + bf2f(a.z) + bf2f(a.w)
           + bf2f(d.x) + bf2f(d.y) + bf2f(d.z) + bf2f(d.w);
    }
    dst[((size_t)b * GG + g) * 27 + c] = s * (1.f / 64.f);
}

// ---------------- 4a. patch attention S partials ----------------
__global__ void k_spart(const __hip_bfloat16* __restrict__ q, const __hip_bfloat16* __restrict__ k,
                        float* __restrict__ spart) {
    int blk = blockIdx.x;                 // BB*14*16 = 896
    int ds = blk & 15;
    int t = blk >> 4;
    int nt = t % 14;
    int b = t / 14;
    int n0 = nt * 14;
    int m = threadIdx.x < 196 ? threadIdx.x : 195;
    const ushort* qb_ = (const ushort*)q + (size_t)b * CHW;
    const ushort* kb_ = (const ushort*)k + (size_t)b * CHW;
    float acc[14];
#pragma unroll
    for (int j = 0; j < 14; j++) acc[j] = 0.f;
    int d0 = ds * DCHUNK;
    for (int d = d0; d < d0 + DCHUNK; ++d) {
        float kv = bf2f(kb_[(size_t)d * NP + m]);
        const uint32_t* qr = reinterpret_cast<const uint32_t*>(qb_ + (size_t)d * NP + n0);
#pragma unroll
        for (int tt = 0; tt < 7; tt++) {
            uint32_t u = qr[tt];
            float qlo = __uint_as_float(u << 16);
            float qhi = __uint_as_float(u & 0xffff0000u);
            acc[2 * tt] += qlo * kv;
            acc[2 * tt + 1] += qhi * kv;
        }
    }
    if (threadIdx.x < 196) {
        size_t base = ((size_t)(b * 16 + ds) * NP) * NP;
#pragma unroll
        for (int j = 0; j < 14; j++)
            spart[base + (size_t)(n0 + j) * NP + m] = acc[j];
    }
}

// ---------------- 4b. reduce + row softmax -> wT[b][m][n] ----------------
__global__ void k_softmax(const float* __restrict__ spart, float* __restrict__ wT) {
    int blk = blockIdx.x;        // BB*196
    int n = blk % NP;
    int b = blk / NP;
    int m = threadIdx.x;
    float val = -1e30f;
    if (m < 196) {
        float s = 0.f;
#pragma unroll
        for (int ds = 0; ds < 16; ds++)
            s += spart[((size_t)(b * 16 + ds) * NP + n) * NP + m];
        val = s * SCALE_P;
    }
    float mx = val;
    for (int o = 32; o; o >>= 1) mx = fmaxf(mx, __shfl_xor(mx, o));
    __shared__ float redm[4], reds[4];
    int wid = threadIdx.x >> 6, lane = threadIdx.x & 63;
    if (lane == 0) redm[wid] = mx;
    __syncthreads();
    mx = fmaxf(fmaxf(redm[0], redm[1]), fmaxf(redm[2], redm[3]));
    float p = (m < 196) ? __expf(val - mx) : 0.f;
    float sm = p;
    for (int o = 32; o; o >>= 1) sm += __shfl_xor(sm, o);
    if (lane == 0) reds[wid] = sm;
    __syncthreads();
    sm = reds[0] + reds[1] + reds[2] + reds[3];
    if (m < 196)
        wT[((size_t)b * NP + m) * NP + n] = p / sm;
}

// ---------------- 5. global pooled attention (flash, 1 wave / row) ----------------
__global__ void k_gattn(const float* __restrict__ qg, const float* __restrict__ kg,
                        const float* __restrict__ vg, float* __restrict__ hg) {
    int wid = threadIdx.x >> 6, lane = threadIdx.x & 63;
    int row = blockIdx.x * 4 + wid;         // 0..12543
    int b = row / GG;
    int i = row - b * GG;
    const float* qr = qg + ((size_t)b * GG + i) * 27;
    float qv[27];
#pragma unroll
    for (int c = 0; c < 27; c++) qv[c] = qr[c];
    float m = -1e30f, l = 0.f;
    float acc[27];
#pragma unroll
    for (int c = 0; c < 27; c++) acc[c] = 0.f;
    for (int it = 0; it < GG / 64; ++it) {
        int j = it * 64 + lane;
        const float* kr = kg + ((size_t)b * GG + j) * 27;
        float s = 0.f;
#pragma unroll
        for (int c = 0; c < 27; c++) s += qv[c] * kr[c];
        s *= SCALE_G;
        float nm = fmaxf(m, s);
        float corr = __expf(m - nm);
        float p = __expf(s - nm);
        l = l * corr + p;
        const float* vr = vg + ((size_t)b * GG + j) * 27;
#pragma unroll
        for (int c = 0; c < 27; c++) acc[c] = acc[c] * corr + p * vr[c];
        m = nm;
    }
    // cross-lane merge
    float gm = m;
    for (int o = 32; o; o >>= 1) gm = fmaxf(gm, __shfl_xor(gm, o));
    float f = __expf(m - gm);
    l *= f;
    for (int o = 32; o; o >>= 1) l += __shfl_xor(l, o);
#pragma unroll
    for (int c = 0; c < 27; c++) {
        float a = acc[c] * f;
        for (int o = 32; o; o >>= 1) a += __shfl_xor(a, o);
        acc[c] = a;
    }
    if (lane == 0) {
        float inv = 1.f / l;
        float* hr = hg + ((size_t)b * GG + i) * 27;
#pragma unroll
        for (int c = 0; c < 27; c++) hr[c] = acc[c] * inv;
    }
}

// ---------------- 6. final: h_patch GEMV + blend + proj + residual ----------------
__global__ void k_final(const float* __restrict__ x, const __hip_bfloat16* __restrict__ v,
                        const float* __restrict__ wT, const float* __restrict__ hg,
                        const float* __restrict__ projw, float* __restrict__ out) {
    __shared__ __align__(16) float vs[27 * 196];
    __shared__ float pw[729];
    int blk = blockIdx.x;           // BB*1024
    int b = blk >> 10;
    int strip = blk & 1023;
    const ushort* vp = (const ushort*)v + (size_t)b * CHW + (size_t)strip * NP;
    for (int idx = threadIdx.x; idx < 27 * 196; idx += 256) {
        int c = idx / 196, j = idx - (idx / 196) * 196;
        vs[idx] = bf2f(vp[(size_t)c * HW + j]);
    }
    for (int idx = threadIdx.x; idx < 729; idx += 256) pw[idx] = projw[idx];
    __syncthreads();
    if (threadIdx.x < 196) {
        int i = threadIdx.x;
        int hw = strip * NP + i;
        int h = hw / 448;
        int w = hw - h * 448;
        int g = (h >> 3) * 56 + (w >> 3);
        const float* wrow = wT + (size_t)b * NP * NP;
        float acc[27];
#pragma unroll
        for (int c = 0; c < 27; c++) acc[c] = 0.f;
        for (int j4 = 0; j4 < 196; j4 += 4) {
            float w0 = wrow[(j4 + 0) * NP + i];
            float w1 = wrow[(j4 + 1) * NP + i];
            float w2 = wrow[(j4 + 2) * NP + i];
            float w3 = wrow[(j4 + 3) * NP + i];
#pragma unroll
            for (int c = 0; c < 27; c++) {
                const float4 vv = *reinterpret_cast<const float4*>(&vs[c * 196 + j4]);
                acc[c] += vv.x * w0 + vv.y * w1 + vv.z * w2 + vv.w * w3;
            }
        }
        const float* hgr = hg + ((size_t)b * GG + g) * 27;
        float hin[27];
#pragma unroll
        for (int c = 0; c < 27; c++) hin[c] = 0.75f * acc[c] + 0.25f * hgr[c];
        size_t ob = (size_t)b * CHW + hw;
#pragma unroll 1
        for (int o = 0; o < 27; o++) {
            float r = 0.f;
#pragma unroll
            for (int c = 0; c < 27; c++) r += pw[o * 27 + c] * hin[c];
            out[ob + (size_t)o * HW] = x[ob + (size_t)o * HW] + r;
        }
    }
}

// ---------------- launch ----------------
extern "C" void kernel_launch(void* const* d_in, const int* in_sizes, int n_in,
                              void* d_out, int out_size, void* d_ws, size_t ws_size,
                              hipStream_t stream) {
    const float* x    = (const float*)d_in[0];
    const float* gnw  = (const float*)d_in[1];
    const float* gnb  = (const float*)d_in[2];
    const float* qw   = (const float*)d_in[3];
    const float* qb   = (const float*)d_in[4];
    const float* kw   = (const float*)d_in[5];
    const float* kb   = (const float*)d_in[6];
    const float* vw   = (const float*)d_in[7];
    const float* vb   = (const float*)d_in[8];
    const float* pjw  = (const float*)d_in[9];
    float* out = (float*)d_out;

    char* ws = (char*)d_ws;
    size_t off = 0;
    auto alloc = [&](size_t bytes) { void* p = ws + off; off += (bytes + 255) & ~(size_t)255; return p; };
    __hip_bfloat16* qbf = (__hip_bfloat16*)alloc((size_t)BB * CHW * 2);
    __hip_bfloat16* kbf = (__hip_bfloat16*)alloc((size_t)BB * CHW * 2);
    __hip_bfloat16* vbf = (__hip_bfloat16*)alloc((size_t)BB * CHW * 2);
    float* spart = (float*)alloc((size_t)BB * 16 * NP * NP * 4);
    float* wT    = (float*)alloc((size_t)BB * NP * NP * 4);
    float* qg    = (float*)alloc((size_t)BB * GG * 27 * 4);
    float* kg    = (float*)alloc((size_t)BB * GG * 27 * 4);
    float* vg    = (float*)alloc((size_t)BB * GG * 27 * 4);
    float* hg    = (float*)alloc((size_t)BB * GG * 27 * 4);
    float* part  = (float*)alloc((size_t)BB * 1024 * 2 * 4);
    float* stats = (float*)alloc((size_t)BB * 2 * 4);

    k_gn_partial<<<BB * 1024, 256, 0, stream>>>(x, part);
    k_gn_final<<<BB, 256, 0, stream>>>(part, stats);
    k_qkv<<<(BB * HW) / 256, 256, 0, stream>>>(x, stats, qw, qb, kw, kb, vw, vb, gnw, gnb,
                                               qbf, kbf, vbf);
    k_pool<<<(BB * 27 * GG) / 256, 256, 0, stream>>>(qbf, qg);
    k_pool<<<(BB * 27 * GG) / 256, 256, 0, stream>>>(kbf, kg);
    k_pool<<<(BB * 27 * GG) / 256, 256, 0, stream>>>(vbf, vg);
    k_spart<<<BB * 14 * 16, 256, 0, stream>>>(qbf, kbf, spart);
    k_softmax<<<BB * NP, 256, 0, stream>>>(spart, wT);
    k_gattn<<<(BB * GG) / 4, 256, 0, stream>>>(qg, kg, vg, hg);
    k_final<<<BB * 1024, 256, 0, stream>>>(x, vbf, wT, hg, pjw, out);
}

// Round 2
// 938.688 us; speedup vs baseline: 1.3815x; 1.3815x over previous
//
#include <hip/hip_runtime.h>
#include <hip/hip_bf16.h>
#include <cstdint>

// ---------------- problem constants ----------------
namespace {
constexpr int BB = 4;
constexpr int CC = 27;
constexpr int HW = 448 * 448;                 // 200704
constexpr long long CHW = (long long)CC * HW; // 5419008
constexpr int NP = 196;                        // patch positions
constexpr int NSTRIP = HW / NP;                // 1024
constexpr int GG = 56 * 56;                    // 3136 pooled positions
constexpr int DSPLIT = 16;
constexpr int DTOT = CC * NSTRIP;              // 27648
constexpr int DCHUNK = DTOT / DSPLIT;          // 1728
constexpr float SCALE_P = 0.0060140449f;       // 1/sqrt(27648)
constexpr float SCALE_G = 0.1924500897f;       // 1/sqrt(27)
constexpr float EPSV = 1e-5f;
constexpr int KSPLIT = 32;                     // key splits for global attn
constexpr int KPB = GG / KSPLIT;               // 98 keys per block
}

__device__ __forceinline__ float bf2f(unsigned short u) {
    return __uint_as_float(((uint32_t)u) << 16);
}

// ---------------- 1. GroupNorm stats ----------------
__global__ void k_gn_partial(const float* __restrict__ x, float* __restrict__ part) {
    int blk = blockIdx.x;          // BB*1024 blocks
    int b = blk >> 10;
    int chunk = blk & 1023;
    const int CLEN = (int)(CHW / 1024);   // 5292
    const float* p = x + (size_t)b * CHW + (size_t)chunk * CLEN;
    float s = 0.f, ss = 0.f;
    for (int i = threadIdx.x; i < CLEN; i += 256) {
        float v = p[i];
        s += v; ss += v * v;
    }
    for (int o = 32; o; o >>= 1) { s += __shfl_down(s, o); ss += __shfl_down(ss, o); }
    __shared__ float ls[4], lss[4];
    int wid = threadIdx.x >> 6, lane = threadIdx.x & 63;
    if (lane == 0) { ls[wid] = s; lss[wid] = ss; }
    __syncthreads();
    if (threadIdx.x == 0) {
        float S = ls[0] + ls[1] + ls[2] + ls[3];
        float SS = lss[0] + lss[1] + lss[2] + lss[3];
        part[blk * 2] = S; part[blk * 2 + 1] = SS;
    }
}

__global__ void k_gn_final(const float* __restrict__ part, float* __restrict__ stats) {
    int b = blockIdx.x;
    float s = 0.f, ss = 0.f;
    for (int i = threadIdx.x; i < 1024; i += 256) {
        s += part[(b * 1024 + i) * 2];
        ss += part[(b * 1024 + i) * 2 + 1];
    }
    for (int o = 32; o; o >>= 1) { s += __shfl_down(s, o); ss += __shfl_down(ss, o); }
    __shared__ float ls[4], lss[4];
    int wid = threadIdx.x >> 6, lane = threadIdx.x & 63;
    if (lane == 0) { ls[wid] = s; lss[wid] = ss; }
    __syncthreads();
    if (threadIdx.x == 0) {
        float S = ls[0] + ls[1] + ls[2] + ls[3];
        float SS = lss[0] + lss[1] + lss[2] + lss[3];
        float mean = S / (float)CHW;
        float var = SS / (float)CHW - mean * mean;
        stats[b * 2] = mean;
        stats[b * 2 + 1] = rsqrtf(var + EPSV);
    }
}

// ---------------- 2. GN-apply + QKV conv1x1 (-> bf16) ----------------
__global__ void k_qkv(const float* __restrict__ x, const float* __restrict__ stats,
                      const float* __restrict__ qw, const float* __restrict__ qb,
                      const float* __restrict__ kw, const float* __restrict__ kb,
                      const float* __restrict__ vw, const float* __restrict__ vb,
                      const float* __restrict__ gnw, const float* __restrict__ gnb,
                      __hip_bfloat16* __restrict__ q, __hip_bfloat16* __restrict__ k,
                      __hip_bfloat16* __restrict__ v) {
    __shared__ float W[2322];
    for (int i = threadIdx.x; i < 729; i += 256) {
        W[i] = qw[i]; W[729 + i] = kw[i]; W[1458 + i] = vw[i];
    }
    if (threadIdx.x < 27) {
        int i = threadIdx.x;
        W[2187 + i] = qb[i]; W[2214 + i] = kb[i]; W[2241 + i] = vb[i];
        W[2268 + i] = gnw[i]; W[2295 + i] = gnb[i];
    }
    __syncthreads();
    int p = blockIdx.x * 256 + threadIdx.x;   // 0..802815
    int b = p / HW;
    int hw = p - b * HW;
    float mean = stats[b * 2], rstd = stats[b * 2 + 1];
    float xn[27];
    const float* xp = x + (size_t)b * CHW + hw;
#pragma unroll
    for (int c = 0; c < 27; c++)
        xn[c] = (xp[(size_t)c * HW] - mean) * rstd * W[2268 + c] + W[2295 + c];
    size_t ob = (size_t)b * CHW + hw;
#pragma unroll 1
    for (int o = 0; o < 27; o++) {
        float aq = W[2187 + o], ak = W[2214 + o], av = W[2241 + o];
#pragma unroll
        for (int c = 0; c < 27; c++) {
            float xv = xn[c];
            aq += W[o * 27 + c] * xv;
            ak += W[729 + o * 27 + c] * xv;
            av += W[1458 + o * 27 + c] * xv;
        }
        q[ob + (size_t)o * HW] = __float2bfloat16(aq);
        k[ob + (size_t)o * HW] = __float2bfloat16(ak);
        v[ob + (size_t)o * HW] = __float2bfloat16(av);
    }
}

// ---------------- 3. 8x8 avg pool -> transposed [b][g][27] ----------------
__global__ void k_pool(const __hip_bfloat16* __restrict__ src, float* __restrict__ dst) {
    int idx = blockIdx.x * 256 + threadIdx.x;  // < 4*27*3136 = 338688
    int g = idx % GG;
    int t = idx / GG;
    int c = t % 27;
    int b = t / 27;
    int gh = g / 56, gw = g - (g / 56) * 56;
    const ushort* sp = (const ushort*)src + (size_t)(b * 27 + c) * HW + (size_t)(gh * 8) * 448 + gw * 8;
    float s = 0.f;
#pragma unroll
    for (int r = 0; r < 8; r++) {
        const ushort4 a = *reinterpret_cast<const ushort4*>(sp + r * 448);
        const ushort4 d = *reinterpret_cast<const ushort4*>(sp + r * 448 + 4);
        s += bf2f(a.x) + bf2f(a.y) + bf2f(a.z) + bf2f(a.w)
           + bf2f(d.x) + bf2f(d.y) + bf2f(d.z) + bf2f(d.w);
    }
    dst[((size_t)b * GG + g) * 27 + c] = s * (1.f / 64.f);
}

// ---------------- 4a. patch attention S partials ----------------
__global__ void k_spart(const __hip_bfloat16* __restrict__ q, const __hip_bfloat16* __restrict__ k,
                        float* __restrict__ spart) {
    int blk = blockIdx.x;                 // BB*14*16 = 896
    int ds = blk & 15;
    int t = blk >> 4;
    int nt = t % 14;
    int b = t / 14;
    int n0 = nt * 14;
    int m = threadIdx.x < 196 ? threadIdx.x : 195;
    const ushort* qb_ = (const ushort*)q + (size_t)b * CHW;
    const ushort* kb_ = (const ushort*)k + (size_t)b * CHW;
    float acc[14];
#pragma unroll
    for (int j = 0; j < 14; j++) acc[j] = 0.f;
    int d0 = ds * DCHUNK;
    for (int d = d0; d < d0 + DCHUNK; ++d) {
        float kv = bf2f(kb_[(size_t)d * NP + m]);
        const uint32_t* qr = reinterpret_cast<const uint32_t*>(qb_ + (size_t)d * NP + n0);
#pragma unroll
        for (int tt = 0; tt < 7; tt++) {
            uint32_t u = qr[tt];
            float qlo = __uint_as_float(u << 16);
            float qhi = __uint_as_float(u & 0xffff0000u);
            acc[2 * tt] += qlo * kv;
            acc[2 * tt + 1] += qhi * kv;
        }
    }
    if (threadIdx.x < 196) {
        size_t base = ((size_t)(b * 16 + ds) * NP) * NP;
#pragma unroll
        for (int j = 0; j < 14; j++)
            spart[base + (size_t)(n0 + j) * NP + m] = acc[j];
    }
}

// ---------------- 4b. reduce + row softmax -> wT[b][m][n] ----------------
__global__ void k_softmax(const float* __restrict__ spart, float* __restrict__ wT) {
    int blk = blockIdx.x;        // BB*196
    int n = blk % NP;
    int b = blk / NP;
    int m = threadIdx.x;
    float val = -1e30f;
    if (m < 196) {
        float s = 0.f;
#pragma unroll
        for (int ds = 0; ds < 16; ds++)
            s += spart[((size_t)(b * 16 + ds) * NP + n) * NP + m];
        val = s * SCALE_P;
    }
    float mx = val;
    for (int o = 32; o; o >>= 1) mx = fmaxf(mx, __shfl_xor(mx, o));
    __shared__ float redm[4], reds[4];
    int wid = threadIdx.x >> 6, lane = threadIdx.x & 63;
    if (lane == 0) redm[wid] = mx;
    __syncthreads();
    mx = fmaxf(fmaxf(redm[0], redm[1]), fmaxf(redm[2], redm[3]));
    float p = (m < 196) ? __expf(val - mx) : 0.f;
    float sm = p;
    for (int o = 32; o; o >>= 1) sm += __shfl_xor(sm, o);
    if (lane == 0) reds[wid] = sm;
    __syncthreads();
    sm = reds[0] + reds[1] + reds[2] + reds[3];
    if (m < 196)
        wT[((size_t)b * NP + m) * NP + n] = p / sm;
}

// ---------------- 5a. global pooled attention: split-K partials ----------------
// scores are tiny (|s| < ~2): softmax without max-subtraction is exact in fp32,
// so partial (l, acc) over key subsets sum directly.
__global__ __launch_bounds__(256, 1)
void k_gattn_part(const float* __restrict__ qg, const float* __restrict__ kg,
                  const float* __restrict__ vg, float* __restrict__ pacc,
                  float* __restrict__ pl) {
    __shared__ __align__(16) float ksh[KPB * 28];
    __shared__ __align__(16) float vsh[KPB * 28];
    int blk = blockIdx.x;            // 4b * 4qblk * 32ks = 512
    int ks = blk & 31;
    int qblk = (blk >> 5) & 3;
    int b = blk >> 7;

    for (int idx = threadIdx.x; idx < KPB * 28; idx += 256) {
        int r = idx / 28, c = idx - (idx / 28) * 28;
        int g = ks * KPB + r;
        float kvv = 0.f, vvv = 0.f;
        if (c < 27) {
            kvv = kg[((size_t)b * GG + g) * 27 + c];
            vvv = vg[((size_t)b * GG + g) * 27 + c];
        }
        ksh[idx] = kvv; vsh[idx] = vvv;
    }
    __syncthreads();

    float q[4][28], acc[4][28];
    int qbase = qblk * 1024 + threadIdx.x;
#pragma unroll
    for (int qq = 0; qq < 4; qq++) {
#pragma unroll
        for (int c = 0; c < 28; c++) { q[qq][c] = 0.f; acc[qq][c] = 0.f; }
        int qi = qbase + qq * 256;
        if (qi < GG) {
            const float* qr = qg + ((size_t)b * GG + qi) * 27;
#pragma unroll
            for (int c = 0; c < 27; c++) q[qq][c] = qr[c];
        }
    }
    float l0 = 0.f, l1 = 0.f, l2 = 0.f, l3 = 0.f;

    for (int j = 0; j < KPB; j++) {
        const float4* kr = reinterpret_cast<const float4*>(ksh + j * 28);
        float s0 = 0.f, s1 = 0.f, s2 = 0.f, s3 = 0.f;
#pragma unroll
        for (int t = 0; t < 7; t++) {
            float4 kk = kr[t];
            s0 += q[0][4*t]*kk.x + q[0][4*t+1]*kk.y + q[0][4*t+2]*kk.z + q[0][4*t+3]*kk.w;
            s1 += q[1][4*t]*kk.x + q[1][4*t+1]*kk.y + q[1][4*t+2]*kk.z + q[1][4*t+3]*kk.w;
            s2 += q[2][4*t]*kk.x + q[2][4*t+1]*kk.y + q[2][4*t+2]*kk.z + q[2][4*t+3]*kk.w;
            s3 += q[3][4*t]*kk.x + q[3][4*t+1]*kk.y + q[3][4*t+2]*kk.z + q[3][4*t+3]*kk.w;
        }
        float p0 = __expf(s0 * SCALE_G);
        float p1 = __expf(s1 * SCALE_G);
        float p2 = __expf(s2 * SCALE_G);
        float p3 = __expf(s3 * SCALE_G);
        l0 += p0; l1 += p1; l2 += p2; l3 += p3;
        const float4* vr = reinterpret_cast<const float4*>(vsh + j * 28);
#pragma unroll
        for (int t = 0; t < 7; t++) {
            float4 vv = vr[t];
            acc[0][4*t] += p0*vv.x; acc[0][4*t+1] += p0*vv.y; acc[0][4*t+2] += p0*vv.z; acc[0][4*t+3] += p0*vv.w;
            acc[1][4*t] += p1*vv.x; acc[1][4*t+1] += p1*vv.y; acc[1][4*t+2] += p1*vv.z; acc[1][4*t+3] += p1*vv.w;
            acc[2][4*t] += p2*vv.x; acc[2][4*t+1] += p2*vv.y; acc[2][4*t+2] += p2*vv.z; acc[2][4*t+3] += p2*vv.w;
            acc[3][4*t] += p3*vv.x; acc[3][4*t+1] += p3*vv.y; acc[3][4*t+2] += p3*vv.z; acc[3][4*t+3] += p3*vv.w;
        }
    }

    float lv[4] = {l0, l1, l2, l3};
#pragma unroll
    for (int qq = 0; qq < 4; qq++) {
        int qi = qbase + qq * 256;
        if (qi < GG) {
            size_t base = ((size_t)(b * KSPLIT + ks) * GG + qi);
            pl[base] = lv[qq];
            float* pa = pacc + base * 27;
#pragma unroll
            for (int c = 0; c < 27; c++) pa[c] = acc[qq][c];
        }
    }
}

// ---------------- 5b. combine split-K partials ----------------
__global__ void k_gattn_reduce(const float* __restrict__ pacc, const float* __restrict__ pl,
                               float* __restrict__ hg) {
    int t = blockIdx.x * 256 + threadIdx.x;   // < BB*GG*27 = 338688
    if (t >= BB * GG * 27) return;
    int c = t % 27;
    int g = (t / 27) % GG;
    int b = t / (27 * GG);
    float l = 0.f, a = 0.f;
#pragma unroll
    for (int ks = 0; ks < KSPLIT; ks++) {
        size_t base = ((size_t)(b * KSPLIT + ks) * GG + g);
        l += pl[base];
        a += pacc[base * 27 + c];
    }
    hg[((size_t)b * GG + g) * 27 + c] = a / l;
}

// ---------------- 6. final: h_patch GEMV + blend + proj + residual ----------------
__global__ void k_final(const float* __restrict__ x, const __hip_bfloat16* __restrict__ v,
                        const float* __restrict__ wT, const float* __restrict__ hg,
                        const float* __restrict__ projw, float* __restrict__ out) {
    __shared__ __align__(16) float vs[27 * 196];
    __shared__ float pw[729];
    int blk = blockIdx.x;           // BB*1024
    int b = blk >> 10;
    int strip = blk & 1023;
    const ushort* vp = (const ushort*)v + (size_t)b * CHW + (size_t)strip * NP;
    for (int idx = threadIdx.x; idx < 27 * 196; idx += 256) {
        int c = idx / 196, j = idx - (idx / 196) * 196;
        vs[idx] = bf2f(vp[(size_t)c * HW + j]);
    }
    for (int idx = threadIdx.x; idx < 729; idx += 256) pw[idx] = projw[idx];
    __syncthreads();
    if (threadIdx.x < 196) {
        int i = threadIdx.x;
        int hw = strip * NP + i;
        int h = hw / 448;
        int w = hw - h * 448;
        int g = (h >> 3) * 56 + (w >> 3);
        const float* wrow = wT + (size_t)b * NP * NP;
        float acc[27];
#pragma unroll
        for (int c = 0; c < 27; c++) acc[c] = 0.f;
        for (int j4 = 0; j4 < 196; j4 += 4) {
            float w0 = wrow[(j4 + 0) * NP + i];
            float w1 = wrow[(j4 + 1) * NP + i];
            float w2 = wrow[(j4 + 2) * NP + i];
            float w3 = wrow[(j4 + 3) * NP + i];
#pragma unroll
            for (int c = 0; c < 27; c++) {
                const float4 vv = *reinterpret_cast<const float4*>(&vs[c * 196 + j4]);
                acc[c] += vv.x * w0 + vv.y * w1 + vv.z * w2 + vv.w * w3;
            }
        }
        const float* hgr = hg + ((size_t)b * GG + g) * 27;
        float hin[27];
#pragma unroll
        for (int c = 0; c < 27; c++) hin[c] = 0.75f * acc[c] + 0.25f * hgr[c];
        size_t ob = (size_t)b * CHW + hw;
#pragma unroll 1
        for (int o = 0; o < 27; o++) {
            float r = 0.f;
#pragma unroll
            for (int c = 0; c < 27; c++) r += pw[o * 27 + c] * hin[c];
            out[ob + (size_t)o * HW] = x[ob + (size_t)o * HW] + r;
        }
    }
}

// ---------------- launch ----------------
extern "C" void kernel_launch(void* const* d_in, const int* in_sizes, int n_in,
                              void* d_out, int out_size, void* d_ws, size_t ws_size,
                              hipStream_t stream) {
    const float* x    = (const float*)d_in[0];
    const float* gnw  = (const float*)d_in[1];
    const float* gnb  = (const float*)d_in[2];
    const float* qw   = (const float*)d_in[3];
    const float* qb   = (const float*)d_in[4];
    const float* kw   = (const float*)d_in[5];
    const float* kb   = (const float*)d_in[6];
    const float* vw   = (const float*)d_in[7];
    const float* vb   = (const float*)d_in[8];
    const float* pjw  = (const float*)d_in[9];
    float* out = (float*)d_out;

    char* ws = (char*)d_ws;
    size_t off = 0;
    auto alloc = [&](size_t bytes) { void* p = ws + off; off += (bytes + 255) & ~(size_t)255; return p; };
    __hip_bfloat16* qbf = (__hip_bfloat16*)alloc((size_t)BB * CHW * 2);
    __hip_bfloat16* kbf = (__hip_bfloat16*)alloc((size_t)BB * CHW * 2);
    __hip_bfloat16* vbf = (__hip_bfloat16*)alloc((size_t)BB * CHW * 2);
    float* spart = (float*)alloc((size_t)BB * 16 * NP * NP * 4);
    float* wT    = (float*)alloc((size_t)BB * NP * NP * 4);
    float* qg    = (float*)alloc((size_t)BB * GG * 27 * 4);
    float* kg    = (float*)alloc((size_t)BB * GG * 27 * 4);
    float* vg    = (float*)alloc((size_t)BB * GG * 27 * 4);
    float* hg    = (float*)alloc((size_t)BB * GG * 27 * 4);
    float* part  = (float*)alloc((size_t)BB * 1024 * 2 * 4);
    float* stats = (float*)alloc((size_t)BB * 2 * 4);
    float* pacc  = (float*)alloc((size_t)BB * KSPLIT * GG * 27 * 4);
    float* pl    = (float*)alloc((size_t)BB * KSPLIT * GG * 4);

    k_gn_partial<<<BB * 1024, 256, 0, stream>>>(x, part);
    k_gn_final<<<BB, 256, 0, stream>>>(part, stats);
    k_qkv<<<(BB * HW) / 256, 256, 0, stream>>>(x, stats, qw, qb, kw, kb, vw, vb, gnw, gnb,
                                               qbf, kbf, vbf);
    k_pool<<<(BB * 27 * GG) / 256, 256, 0, stream>>>(qbf, qg);
    k_pool<<<(BB * 27 * GG) / 256, 256, 0, stream>>>(kbf, kg);
    k_pool<<<(BB * 27 * GG) / 256, 256, 0, stream>>>(vbf, vg);
    k_spart<<<BB * 14 * 16, 256, 0, stream>>>(qbf, kbf, spart);
    k_softmax<<<BB * NP, 256, 0, stream>>>(spart, wT);
    k_gattn_part<<<BB * 4 * KSPLIT, 256, 0, stream>>>(qg, kg, vg, pacc, pl);
    k_gattn_reduce<<<(BB * GG * 27 + 255) / 256, 256, 0, stream>>>(pacc, pl, hg);
    k_final<<<BB * 1024, 256, 0, stream>>>(x, vbf, wT, hg, pjw, out);
}